// Round 1
// baseline (214.029 us; speedup 1.0000x reference)
//
#include <hip/hip_runtime.h>
#include <math.h>

// Problem constants
#define BB 4
#define SS 2048
#define DD 2048
#define EE 64
#define NTOK (BB*SS)          // 8192 tokens
#define MTILE 64              // tokens per block tile
#define KSPLIT 4              // split of the d-dimension across blocks
#define DPER (DD/KSPLIT)      // 512 d-values per block
#define DCHUNK 32             // d-values staged per LDS chunk
#define KT (2*DCHUNK)         // 64 features (amp+phase) per chunk
#define ATPAD 4               // pad A-tile rows to 68 floats (keeps 16B align, breaks worst conflicts)
#define PROB_N (NTOK*2)       // 16384 floats of probs, then 16384 floats of indices

// Kernel 1: partial scores. Each block: 64 tokens x 64 experts over a 512-wide
// slice of d. amp = sqrt(xr^2+xi^2) feeds W[0:2048,:], phase = atan2(xi,xr)
// feeds W[2048:4096,:]. Accumulate fp32, write partial[ks][token][expert].
__global__ __launch_bounds__(256) void gemm_partial(
    const float* __restrict__ xr, const float* __restrict__ xi,
    const float* __restrict__ W, float* __restrict__ part)
{
    __shared__ __align__(16) float At[KT][MTILE + ATPAD]; // feature-major (transposed A)
    __shared__ __align__(16) float Wt[KT][EE];            // feature-major W tile

    const int bid   = blockIdx.x;
    const int ks    = bid & (KSPLIT - 1);
    const int strip = bid >> 2;
    const int t0    = strip * MTILE;
    const int dbase = ks * DPER;

    const int tid = threadIdx.x;
    const int tn  = tid & 15;   // expert group: experts tn*4..tn*4+3
    const int tm  = tid >> 4;   // token group:  tokens tm*4..tm*4+3

    // staging maps
    const int st_f4 = tid & 7;  // which float4 (of 8) in a 32-d row
    const int st_t  = tid >> 3; // token 0..31 (second rep adds 32)
    const int sw_e4 = tid & 15; // expert float4 (16 per feature row)
    const int sw_k  = tid >> 4; // feature row 0..15 (reps add 16)

    float acc[4][4] = {};

    for (int chunk = 0; chunk < DPER / DCHUNK; ++chunk) {
        const int d0 = dbase + chunk * DCHUNK;

        // ---- stage A: load x, compute amp/phase, write transposed ----
        #pragma unroll
        for (int rep = 0; rep < 2; ++rep) {
            const int t = st_t + rep * 32;
            const float4 vr = *((const float4*)(xr + (size_t)(t0 + t) * DD + d0) + st_f4);
            const float4 vi = *((const float4*)(xi + (size_t)(t0 + t) * DD + d0) + st_f4);
            const int kr = 4 * st_f4;
            At[kr + 0][t] = sqrtf(vr.x * vr.x + vi.x * vi.x);
            At[kr + 1][t] = sqrtf(vr.y * vr.y + vi.y * vi.y);
            At[kr + 2][t] = sqrtf(vr.z * vr.z + vi.z * vi.z);
            At[kr + 3][t] = sqrtf(vr.w * vr.w + vi.w * vi.w);
            At[DCHUNK + kr + 0][t] = atan2f(vi.x, vr.x);
            At[DCHUNK + kr + 1][t] = atan2f(vi.y, vr.y);
            At[DCHUNK + kr + 2][t] = atan2f(vi.z, vr.z);
            At[DCHUNK + kr + 3][t] = atan2f(vi.w, vr.w);
        }
        // ---- stage W tile: rows 0..31 = amp weights, 32..63 = phase weights ----
        #pragma unroll
        for (int rr = 0; rr < 4; ++rr) {
            const int k  = sw_k + rr * 16;
            const int gf = (k < DCHUNK) ? (d0 + k) : (DD + d0 + (k - DCHUNK));
            const float4 wv = *((const float4*)(W + (size_t)gf * EE) + sw_e4);
            *((float4*)&Wt[k][sw_e4 * 4]) = wv;
        }
        __syncthreads();

        // ---- compute: 4x4 register tile over 64 features ----
        #pragma unroll 8
        for (int k = 0; k < KT; ++k) {
            const float4 av = *(const float4*)&At[k][tm * 4];
            const float4 bv = *(const float4*)&Wt[k][tn * 4];
            acc[0][0] += av.x * bv.x; acc[0][1] += av.x * bv.y; acc[0][2] += av.x * bv.z; acc[0][3] += av.x * bv.w;
            acc[1][0] += av.y * bv.x; acc[1][1] += av.y * bv.y; acc[1][2] += av.y * bv.z; acc[1][3] += av.y * bv.w;
            acc[2][0] += av.z * bv.x; acc[2][1] += av.z * bv.y; acc[2][2] += av.z * bv.z; acc[2][3] += av.z * bv.w;
            acc[3][0] += av.w * bv.x; acc[3][1] += av.w * bv.y; acc[3][2] += av.w * bv.z; acc[3][3] += av.w * bv.w;
        }
        __syncthreads();
    }

    // ---- write partial scores: layout [KSPLIT][NTOK][EE] ----
    float* pbase = part + ((size_t)ks * NTOK + t0) * EE;
    #pragma unroll
    for (int i = 0; i < 4; ++i) {
        float4 v = make_float4(acc[i][0], acc[i][1], acc[i][2], acc[i][3]);
        *((float4*)(pbase + (size_t)(tm * 4 + i) * EE + tn * 4)) = v;
    }
}

// Kernel 2: per token, sum KSPLIT partials + bias, exact top-2 via shuffle
// butterfly (tie-break: lower index, matching lax.top_k), write normalized
// top-2 probs and indices (as floats).
__global__ __launch_bounds__(256) void finalize_topk(
    const float* __restrict__ part, const float* __restrict__ bias,
    float* __restrict__ out)
{
    const int tid  = threadIdx.x;
    const int lane = tid & 63;   // = expert
    const int w    = tid >> 6;
    const int t    = blockIdx.x * 4 + w;

    float s = bias[lane];
    #pragma unroll
    for (int p = 0; p < KSPLIT; ++p)
        s += part[((size_t)p * NTOK + t) * EE + lane];

    float v1 = s, v2 = -INFINITY;
    int   i1 = lane, i2 = 64;

    #pragma unroll
    for (int off = 1; off < 64; off <<= 1) {
        const float ov1 = __shfl_xor(v1, off, 64);
        const int   oi1 = __shfl_xor(i1, off, 64);
        const float ov2 = __shfl_xor(v2, off, 64);
        const int   oi2 = __shfl_xor(i2, off, 64);
        // merge sorted pairs (v1>=v2) and (ov1>=ov2) -> top2 of union
        const bool b1 = (ov1 > v1) || (ov1 == v1 && oi1 < i1);
        const float n1 = b1 ? ov1 : v1;  const int ni1 = b1 ? oi1 : i1;
        const float c1 = b1 ? v1  : ov1; const int ci1 = b1 ? i1  : oi1; // loser of tops
        const float c2 = b1 ? ov2 : v2;  const int ci2 = b1 ? oi2 : i2;  // winner's second
        const bool b2 = (c1 > c2) || (c1 == c2 && ci1 < ci2);
        v1 = n1; i1 = ni1;
        v2 = b2 ? c1 : c2; i2 = b2 ? ci1 : ci2;
    }

    if (lane == 0) {
        const float z  = expf(v2 - v1);        // <= 1
        const float p1 = 1.0f / (1.0f + z);
        const float p2 = z / (1.0f + z);
        out[(size_t)t * 2 + 0] = p1;
        out[(size_t)t * 2 + 1] = p2;
        out[PROB_N + (size_t)t * 2 + 0] = (float)i1;
        out[PROB_N + (size_t)t * 2 + 1] = (float)i2;
    }
}

extern "C" void kernel_launch(void* const* d_in, const int* in_sizes, int n_in,
                              void* d_out, int out_size, void* d_ws, size_t ws_size,
                              hipStream_t stream) {
    const float* xr = (const float*)d_in[0];
    const float* xi = (const float*)d_in[1];
    const float* W  = (const float*)d_in[2];
    const float* b  = (const float*)d_in[3];
    float* out  = (float*)d_out;
    float* part = (float*)d_ws;   // KSPLIT * 8192 * 64 * 4 B = 8 MB

    gemm_partial<<<(NTOK / MTILE) * KSPLIT, 256, 0, stream>>>(xr, xi, W, part);
    finalize_topk<<<NTOK / 4, 256, 0, stream>>>(part, b, out);
}

// Round 2
// 195.834 us; speedup vs baseline: 1.0929x; 1.0929x over previous
//
#include <hip/hip_runtime.h>
#include <math.h>

#define NTOK 8192
#define DD   2048
#define EE   64
#define MTILE 32
#define KSPLIT 2
#define DPER (DD/KSPLIT)      // 1024 d-values per block
#define DCHUNK 32             // d-values per staged chunk (64 features)
#define NCHUNK (DPER/DCHUNK)  // 32
#define APAD 8
#define ASTRIDE (64 + APAD)   // 72 ushorts = 144 B rows (16B aligned)
#define PROB_N (NTOK*2)

typedef __bf16 bf16x8 __attribute__((ext_vector_type(8)));
typedef float  f32x4  __attribute__((ext_vector_type(4)));

// RNE truncate fp32 -> bf16 bits + the representable float it denotes
__device__ __forceinline__ unsigned short bf16_rne(float x, float& rep) {
    unsigned u = __builtin_bit_cast(unsigned, x);
    unsigned r = u + 0x7FFFu + ((u >> 16) & 1u);
    unsigned short h = (unsigned short)(r >> 16);
    rep = __builtin_bit_cast(float, (unsigned)h << 16);
    return h;
}

// 3-way bf16 split: x = h1 + h2 + h3 + eps, |eps| <~ 2^-27 |x|
__device__ __forceinline__ void split3(float x, unsigned short& h1,
                                       unsigned short& h2, unsigned short& h3) {
    float f1, f2, f3;
    h1 = bf16_rne(x, f1);
    float r1 = x - f1;
    h2 = bf16_rne(r1, f2);
    float r2 = r1 - f2;
    h3 = bf16_rne(r2, f3);
}

// Kernel 0: split W [4096][64] fp32 into Wt [3][64][4096] bf16 (transposed)
__global__ __launch_bounds__(256) void wsplit(const float* __restrict__ W,
                                              unsigned short* __restrict__ Wt) {
    const int g  = blockIdx.x * 256 + threadIdx.x;   // 65536 threads
    const int f  = g >> 4;
    const int e4 = g & 15;
    const float4 w = *((const float4*)(W + (size_t)f * EE) + e4);
    const float v[4] = {w.x, w.y, w.z, w.w};
    #pragma unroll
    for (int j = 0; j < 4; ++j) {
        unsigned short h1, h2, h3;
        split3(v[j], h1, h2, h3);
        const int e = e4 * 4 + j;
        Wt[((size_t)(0 * EE + e)) * 4096 + f] = h1;
        Wt[((size_t)(1 * EE + e)) * 4096 + f] = h2;
        Wt[((size_t)(2 * EE + e)) * 4096 + f] = h3;
    }
}

// Kernel 1: 32-token x 64-expert tile, K split in 2. amp/phase computed at
// stage time, 3-split to bf16 in LDS; W fragments read straight from L2.
// Six MFMA products reconstruct fp32-precision scores.
__global__ __launch_bounds__(256) void gemm_mfma(
    const float* __restrict__ xr, const float* __restrict__ xi,
    const unsigned short* __restrict__ Wt, float* __restrict__ part)
{
    __shared__ __align__(16) unsigned short As[3][MTILE][ASTRIDE];

    const int bid   = blockIdx.x;
    const int ks    = bid & (KSPLIT - 1);
    const int strip = bid >> 1;
    const int t0    = strip * MTILE;
    const int dbase = ks * DPER;

    const int tid  = threadIdx.x;
    const int lane = tid & 63;
    const int wv   = tid >> 6;     // wave 0..3 -> expert tile n0
    const int n0   = wv * 16;

    const int stok = tid >> 3;     // staging: token 0..31
    const int sf4  = tid & 7;      // staging: d-offset 4*sf4 within chunk

    const int fm = lane & 15;      // frag row/col
    const int fq = lane >> 4;      // frag quad

    f32x4 acc[2][3];
    #pragma unroll
    for (int mt = 0; mt < 2; ++mt)
        #pragma unroll
        for (int g = 0; g < 3; ++g)
            acc[mt][g] = (f32x4){0.f, 0.f, 0.f, 0.f};

    const float* prx = xr + (size_t)(t0 + stok) * DD + dbase + 4 * sf4;
    const float* pix = xi + (size_t)(t0 + stok) * DD + dbase + 4 * sf4;
    float4 vr = *(const float4*)prx;
    float4 vi = *(const float4*)pix;

    // B-frag base: expert row (n0+fm), k-offset 8*fq; split stride 64*4096
    const unsigned short* wb = Wt + (size_t)(n0 + fm) * 4096 + 8 * fq;

    for (int c = 0; c < NCHUNK; ++c) {
        const int d0 = dbase + c * DCHUNK;

        // prefetch B fragments for both k-steps of this chunk (L2-resident)
        bf16x8 bfr[2][3];
        #pragma unroll
        for (int s = 0; s < 3; ++s) {
            bfr[0][s] = *(const bf16x8*)(wb + (size_t)s * (EE * 4096) + d0);
            bfr[1][s] = *(const bf16x8*)(wb + (size_t)s * (EE * 4096) + 2048 + d0);
        }
        // prefetch next chunk's x
        const int cn = (c + 1 < NCHUNK) ? (c + 1) : c;
        const float4 nvr = *(const float4*)(prx + cn * DCHUNK);
        const float4 nvi = *(const float4*)(pix + cn * DCHUNK);

        // amp/phase + 3-split -> LDS (amp at k=4*sf4, phase at k=32+4*sf4)
        {
            const float ar[4] = {vr.x, vr.y, vr.z, vr.w};
            const float ai[4] = {vi.x, vi.y, vi.z, vi.w};
            ushort4 a1, a2, a3, p1, p2, p3;
            unsigned short* pa1 = (unsigned short*)&a1;
            unsigned short* pa2 = (unsigned short*)&a2;
            unsigned short* pa3 = (unsigned short*)&a3;
            unsigned short* pp1 = (unsigned short*)&p1;
            unsigned short* pp2 = (unsigned short*)&p2;
            unsigned short* pp3 = (unsigned short*)&p3;
            #pragma unroll
            for (int j = 0; j < 4; ++j) {
                const float amp = sqrtf(ar[j] * ar[j] + ai[j] * ai[j]);
                const float ph  = atan2f(ai[j], ar[j]);
                split3(amp, pa1[j], pa2[j], pa3[j]);
                split3(ph,  pp1[j], pp2[j], pp3[j]);
            }
            *(ushort4*)&As[0][stok][4 * sf4]      = a1;
            *(ushort4*)&As[1][stok][4 * sf4]      = a2;
            *(ushort4*)&As[2][stok][4 * sf4]      = a3;
            *(ushort4*)&As[0][stok][32 + 4 * sf4] = p1;
            *(ushort4*)&As[1][stok][32 + 4 * sf4] = p2;
            *(ushort4*)&As[2][stok][32 + 4 * sf4] = p3;
        }
        __syncthreads();

        // 2 k-steps x 2 m-tiles x 6 split-products
        #pragma unroll
        for (int st = 0; st < 2; ++st) {
            #pragma unroll
            for (int mt = 0; mt < 2; ++mt) {
                const unsigned short* ab = &As[0][mt * 16 + fm][st * 32 + fq * 8];
                const bf16x8 a0 = *(const bf16x8*)(ab);
                const bf16x8 a1 = *(const bf16x8*)(ab + MTILE * ASTRIDE);
                const bf16x8 a2 = *(const bf16x8*)(ab + 2 * MTILE * ASTRIDE);
                acc[mt][0] = __builtin_amdgcn_mfma_f32_16x16x32_bf16(a0, bfr[st][0], acc[mt][0], 0, 0, 0);
                acc[mt][0] = __builtin_amdgcn_mfma_f32_16x16x32_bf16(a1, bfr[st][1], acc[mt][0], 0, 0, 0);
                acc[mt][1] = __builtin_amdgcn_mfma_f32_16x16x32_bf16(a0, bfr[st][1], acc[mt][1], 0, 0, 0);
                acc[mt][1] = __builtin_amdgcn_mfma_f32_16x16x32_bf16(a1, bfr[st][0], acc[mt][1], 0, 0, 0);
                acc[mt][2] = __builtin_amdgcn_mfma_f32_16x16x32_bf16(a0, bfr[st][2], acc[mt][2], 0, 0, 0);
                acc[mt][2] = __builtin_amdgcn_mfma_f32_16x16x32_bf16(a2, bfr[st][0], acc[mt][2], 0, 0, 0);
            }
        }
        __syncthreads();
        vr = nvr; vi = nvi;
    }

    // epilogue: C/D layout col = lane&15, row = (lane>>4)*4 + reg  [m89]
    #pragma unroll
    for (int mt = 0; mt < 2; ++mt) {
        const f32x4 s = acc[mt][0] + acc[mt][1] + acc[mt][2];
        float* pb = part + ((size_t)ks * NTOK + t0 + mt * 16) * EE;
        #pragma unroll
        for (int r = 0; r < 4; ++r)
            pb[(size_t)(fq * 4 + r) * EE + n0 + fm] = s[r];
    }
}

// Kernel 2: sum KSPLIT partials + bias, exact top-2 via shuffle butterfly
// (tie-break lower index, matching lax.top_k), normalized probs + indices.
__global__ __launch_bounds__(256) void finalize_topk(
    const float* __restrict__ part, const float* __restrict__ bias,
    float* __restrict__ out)
{
    const int tid  = threadIdx.x;
    const int lane = tid & 63;   // = expert
    const int w    = tid >> 6;
    const int t    = blockIdx.x * 4 + w;

    float s = bias[lane];
    #pragma unroll
    for (int p = 0; p < KSPLIT; ++p)
        s += part[((size_t)p * NTOK + t) * EE + lane];

    float v1 = s, v2 = -INFINITY;
    int   i1 = lane, i2 = 64;

    #pragma unroll
    for (int off = 1; off < 64; off <<= 1) {
        const float ov1 = __shfl_xor(v1, off, 64);
        const int   oi1 = __shfl_xor(i1, off, 64);
        const float ov2 = __shfl_xor(v2, off, 64);
        const int   oi2 = __shfl_xor(i2, off, 64);
        const bool b1 = (ov1 > v1) || (ov1 == v1 && oi1 < i1);
        const float n1 = b1 ? ov1 : v1;  const int ni1 = b1 ? oi1 : i1;
        const float c1 = b1 ? v1  : ov1; const int ci1 = b1 ? i1  : oi1;
        const float c2 = b1 ? ov2 : v2;  const int ci2 = b1 ? oi2 : i2;
        const bool b2 = (c1 > c2) || (c1 == c2 && ci1 < ci2);
        v1 = n1; i1 = ni1;
        v2 = b2 ? c1 : c2; i2 = b2 ? ci1 : ci2;
    }

    if (lane == 0) {
        const float z  = expf(v2 - v1);
        const float p1 = 1.0f / (1.0f + z);
        const float p2 = z / (1.0f + z);
        out[(size_t)t * 2 + 0] = p1;
        out[(size_t)t * 2 + 1] = p2;
        out[PROB_N + (size_t)t * 2 + 0] = (float)i1;
        out[PROB_N + (size_t)t * 2 + 1] = (float)i2;
    }
}

extern "C" void kernel_launch(void* const* d_in, const int* in_sizes, int n_in,
                              void* d_out, int out_size, void* d_ws, size_t ws_size,
                              hipStream_t stream) {
    const float* xr = (const float*)d_in[0];
    const float* xi = (const float*)d_in[1];
    const float* W  = (const float*)d_in[2];
    const float* b  = (const float*)d_in[3];
    float* out = (float*)d_out;

    float* part = (float*)d_ws;  // KSPLIT*8192*64*4 = 4 MB
    unsigned short* Wt = (unsigned short*)((char*)d_ws + (size_t)KSPLIT * NTOK * EE * 4);  // 1.5 MB

    wsplit<<<256, 256, 0, stream>>>(W, Wt);
    gemm_mfma<<<(NTOK / MTILE) * KSPLIT, 256, 0, stream>>>(xr, xi, Wt, part);
    finalize_topk<<<NTOK / 4, 256, 0, stream>>>(part, b, out);
}